// Round 6
// baseline (17.664 us; speedup 1.0000x reference)
//
#include <hip/hip_runtime.h>
#include <math.h>

// B=1048576, M=6, N=3. 1 element/thread, branch-free:
// fixed s=3 scaling + Pade(3,3) + adjugate solve + 8 fused mat-vecs.
// Register-minimized (U = A^3 + 60A; V never materialized) and capped to
// <=64 VGPR via __launch_bounds__(256,8) for 8 waves/SIMD latency hiding.
// psi (54 floats) is wave-uniform: scalar s_load path, zero VGPR cost.

// 3x3 row-major matmul: C = A*B
__device__ __forceinline__ void mm3(const float A[9], const float B[9], float C[9]) {
#pragma unroll
    for (int i = 0; i < 3; ++i) {
#pragma unroll
        for (int j = 0; j < 3; ++j) {
            C[i * 3 + j] = fmaf(A[i * 3 + 0], B[0 * 3 + j],
                           fmaf(A[i * 3 + 1], B[1 * 3 + j],
                                A[i * 3 + 2] * B[2 * 3 + j]));
        }
    }
}

__global__ __launch_bounds__(256, 8) void expm_apply1_kernel(
    const float* __restrict__ x,     // [B,3]
    const float* __restrict__ c,     // [B,6]
    const float* __restrict__ psi,   // [54], wave-uniform
    float* __restrict__ out,         // [B,3]
    int B)
{
    int b = blockIdx.x * blockDim.x + threadIdx.x;
    if (b >= B) return;

    // Uniform pointer + constant indices -> compiler emits s_load into SGPRs.
    // (R4 measured readfirstlane == plain scalar loads; plain is cheaper.)
    float sp[54];
#pragma unroll
    for (int i = 0; i < 54; ++i) sp[i] = psi[i];

    // c[b,0..5]: 24B at 8B alignment -> 3x float2
    const float2* c2 = reinterpret_cast<const float2*>(c + (size_t)b * 6);
    float2 ca = c2[0], cb = c2[1], cc = c2[2];
    // fold the 2^-3 scaling into the coefficients: A = (sum c_m psi_m) / 8
    float cm[6] = {ca.x * 0.125f, ca.y * 0.125f, cb.x * 0.125f,
                   cb.y * 0.125f, cc.x * 0.125f, cc.y * 0.125f};

    // x[b,0..2]
    float xv0 = x[(size_t)b * 3 + 0];
    float xv1 = x[(size_t)b * 3 + 1];
    float xv2 = x[(size_t)b * 3 + 2];

    // A = (1/8) * sum_m c[m] * psi[m]   (SGPR operand on psi -> 1 fma each)
    float A[9];
#pragma unroll
    for (int i = 0; i < 9; ++i) {
        float acc = cm[0] * sp[i];
#pragma unroll
        for (int m = 1; m < 6; ++m) acc = fmaf(cm[m], sp[m * 9 + i], acc);
        A[i] = acc;
    }

    float A2[9];
    mm3(A, A, A2);

    // Pade(3,3): U = A*(A2 + 60I) = A^3 + 60A  (no temp matrix)
    float U[9];
    mm3(A, A2, U);
#pragma unroll
    for (int i = 0; i < 9; ++i) U[i] = fmaf(60.f, A[i], U[i]);

    // V = 12*A2 + 120I, never materialized:
    // Mn = V - U, R = V + U directly from A2 and U.
    float Mn[9], R[9];
#pragma unroll
    for (int i = 0; i < 9; ++i) {
        float v = 12.f * A2[i];
        Mn[i] = v - U[i];
        R[i]  = v + U[i];
    }
    Mn[0] += 120.f; Mn[4] += 120.f; Mn[8] += 120.f;
    R[0]  += 120.f; R[4]  += 120.f; R[8]  += 120.f;

    // X = Mn^-1 R via adjugate; Mn ~ 120I - ..., det ~ 120^3, well-conditioned.
    float inv[9];
    inv[0] = Mn[4] * Mn[8] - Mn[5] * Mn[7];
    inv[1] = Mn[2] * Mn[7] - Mn[1] * Mn[8];
    inv[2] = Mn[1] * Mn[5] - Mn[2] * Mn[4];
    inv[3] = Mn[5] * Mn[6] - Mn[3] * Mn[8];
    inv[4] = Mn[0] * Mn[8] - Mn[2] * Mn[6];
    inv[5] = Mn[2] * Mn[3] - Mn[0] * Mn[5];
    inv[6] = Mn[3] * Mn[7] - Mn[4] * Mn[6];
    inv[7] = Mn[1] * Mn[6] - Mn[0] * Mn[7];
    inv[8] = Mn[0] * Mn[4] - Mn[1] * Mn[3];
    float det = Mn[0] * inv[0] + Mn[1] * inv[3] + Mn[2] * inv[6];
    float rdet = __builtin_amdgcn_rcpf(det);  // ~1e-6 rel, plenty for 2% tol

    float X[9];
    mm3(inv, R, X);
#pragma unroll
    for (int i = 0; i < 9; ++i) X[i] *= rdet;

    // y = X^(2^3) @ x = 8 fused mat-vecs (squarings folded into the apply)
    float v0 = xv0, v1 = xv1, v2 = xv2;
#pragma unroll
    for (int k = 0; k < 8; ++k) {
        float w0 = fmaf(X[0], v0, fmaf(X[1], v1, X[2] * v2));
        float w1 = fmaf(X[3], v0, fmaf(X[4], v1, X[5] * v2));
        float w2 = fmaf(X[6], v0, fmaf(X[7], v1, X[8] * v2));
        v0 = w0; v1 = w1; v2 = w2;
    }

    out[(size_t)b * 3 + 0] = v0;
    out[(size_t)b * 3 + 1] = v1;
    out[(size_t)b * 3 + 2] = v2;
}

extern "C" void kernel_launch(void* const* d_in, const int* in_sizes, int n_in,
                              void* d_out, int out_size, void* d_ws, size_t ws_size,
                              hipStream_t stream) {
    const float* x   = (const float*)d_in[0];
    const float* c   = (const float*)d_in[1];
    const float* psi = (const float*)d_in[2];
    float* out = (float*)d_out;
    int B = in_sizes[0] / 3;   // x is [B,3,1]

    int block = 256;
    int grid = (B + block - 1) / block;
    expm_apply1_kernel<<<grid, block, 0, stream>>>(x, c, psi, out, B);
}

// Round 7
// 17.272 us; speedup vs baseline: 1.0227x; 1.0227x over previous
//
#include <hip/hip_runtime.h>
#include <math.h>

// B=1048576, M=6, N=3. 4 elements/thread, pure float4 I/O (3 VMEM/elem),
// elements processed SEQUENTIALLY with the lean R5 math to cap live state:
// fixed s=3 scaling + Pade(3,3) + adjugate solve + 8 fused mat-vecs.
// psi (54 floats, wave-uniform) forced to SGPRs via readfirstlane.

__device__ __forceinline__ float rfl(float v) {
    return __uint_as_float(__builtin_amdgcn_readfirstlane(__float_as_uint(v)));
}

// 3x3 row-major matmul: C = A*B
__device__ __forceinline__ void mm3(const float A[9], const float B[9], float C[9]) {
#pragma unroll
    for (int i = 0; i < 3; ++i) {
#pragma unroll
        for (int j = 0; j < 3; ++j) {
            C[i * 3 + j] = fmaf(A[i * 3 + 0], B[0 * 3 + j],
                           fmaf(A[i * 3 + 1], B[1 * 3 + j],
                                A[i * 3 + 2] * B[2 * 3 + j]));
        }
    }
}

__global__ __launch_bounds__(256) void expm_apply4_kernel(
    const float4* __restrict__ x4,    // float4 view of x [B,3]
    const float4* __restrict__ c4,    // float4 view of c [B,6]
    const float* __restrict__ psi,    // [54], wave-uniform
    float4* __restrict__ out4,        // float4 view of out [B,3]
    int nthread)                      // B/4
{
    int t = blockIdx.x * blockDim.x + threadIdx.x;
    if (t >= nthread) return;

    // psi -> SGPRs (guaranteed): 14 VMEM (L2-hit) + 54 readfirstlane,
    // amortized over 4 elements. Downstream FMAs get free SGPR operand.
    float sp[54];
    {
        const float4* p4 = reinterpret_cast<const float4*>(psi);
#pragma unroll
        for (int i = 0; i < 13; ++i) {
            float4 v = p4[i];
            sp[i * 4 + 0] = rfl(v.x);
            sp[i * 4 + 1] = rfl(v.y);
            sp[i * 4 + 2] = rfl(v.z);
            sp[i * 4 + 3] = rfl(v.w);
        }
        float2 v = reinterpret_cast<const float2*>(psi)[26];
        sp[52] = rfl(v.x);
        sp[53] = rfl(v.y);
    }

    // c: 4 elems x 6 = 24 floats = 6 float4 (96B contiguous per thread).
    // Fold the 2^-3 Pade scaling into the coefficients at load time.
    float4 q0 = c4[(size_t)t * 6 + 0];
    float4 q1 = c4[(size_t)t * 6 + 1];
    float4 q2 = c4[(size_t)t * 6 + 2];
    float4 q3 = c4[(size_t)t * 6 + 3];
    float4 q4 = c4[(size_t)t * 6 + 4];
    float4 q5 = c4[(size_t)t * 6 + 5];
    const float k = 0.125f;
    float cm[4][6] = {
        {q0.x * k, q0.y * k, q0.z * k, q0.w * k, q1.x * k, q1.y * k},
        {q1.z * k, q1.w * k, q2.x * k, q2.y * k, q2.z * k, q2.w * k},
        {q3.x * k, q3.y * k, q3.z * k, q3.w * k, q4.x * k, q4.y * k},
        {q4.z * k, q4.w * k, q5.x * k, q5.y * k, q5.z * k, q5.w * k}};

    // x: 4 elems x 3 = 12 floats = 3 float4 (48B contiguous per thread)
    float4 r0 = x4[(size_t)t * 3 + 0];
    float4 r1 = x4[(size_t)t * 3 + 1];
    float4 r2 = x4[(size_t)t * 3 + 2];
    float xx[4][3] = {{r0.x, r0.y, r0.z},
                      {r0.w, r1.x, r1.y},
                      {r1.z, r1.w, r2.x},
                      {r2.y, r2.z, r2.w}};

    float y[4][3];
#pragma unroll
    for (int e = 0; e < 4; ++e) {
        // A = (1/8) * sum_m c[m] * psi[m]
        float A[9];
#pragma unroll
        for (int i = 0; i < 9; ++i) {
            float acc = cm[e][0] * sp[i];
#pragma unroll
            for (int m = 1; m < 6; ++m) acc = fmaf(cm[e][m], sp[m * 9 + i], acc);
            A[i] = acc;
        }

        float A2[9];
        mm3(A, A, A2);

        // Pade(3,3): U = A*(A2 + 60I) = A^3 + 60A (no temp)
        float U[9];
        mm3(A, A2, U);
#pragma unroll
        for (int i = 0; i < 9; ++i) U[i] = fmaf(60.f, A[i], U[i]);

        // V = 12*A2 + 120I never materialized: Mn = V-U, R = V+U directly.
        float Mn[9], R[9];
#pragma unroll
        for (int i = 0; i < 9; ++i) {
            float v = 12.f * A2[i];
            Mn[i] = v - U[i];
            R[i]  = v + U[i];
        }
        Mn[0] += 120.f; Mn[4] += 120.f; Mn[8] += 120.f;
        R[0]  += 120.f; R[4]  += 120.f; R[8]  += 120.f;

        // X = Mn^-1 R via adjugate; det ~ 120^3, well-conditioned.
        float inv[9];
        inv[0] = Mn[4] * Mn[8] - Mn[5] * Mn[7];
        inv[1] = Mn[2] * Mn[7] - Mn[1] * Mn[8];
        inv[2] = Mn[1] * Mn[5] - Mn[2] * Mn[4];
        inv[3] = Mn[5] * Mn[6] - Mn[3] * Mn[8];
        inv[4] = Mn[0] * Mn[8] - Mn[2] * Mn[6];
        inv[5] = Mn[2] * Mn[3] - Mn[0] * Mn[5];
        inv[6] = Mn[3] * Mn[7] - Mn[4] * Mn[6];
        inv[7] = Mn[1] * Mn[6] - Mn[0] * Mn[7];
        inv[8] = Mn[0] * Mn[4] - Mn[1] * Mn[3];
        float det = Mn[0] * inv[0] + Mn[1] * inv[3] + Mn[2] * inv[6];
        float rdet = __builtin_amdgcn_rcpf(det);

        float X[9];
        mm3(inv, R, X);
#pragma unroll
        for (int i = 0; i < 9; ++i) X[i] *= rdet;

        // y = X^(2^3) @ x = 8 fused mat-vecs
        float v0 = xx[e][0], v1 = xx[e][1], v2 = xx[e][2];
#pragma unroll
        for (int kk = 0; kk < 8; ++kk) {
            float w0 = fmaf(X[0], v0, fmaf(X[1], v1, X[2] * v2));
            float w1 = fmaf(X[3], v0, fmaf(X[4], v1, X[5] * v2));
            float w2 = fmaf(X[6], v0, fmaf(X[7], v1, X[8] * v2));
            v0 = w0; v1 = w1; v2 = w2;
        }
        y[e][0] = v0; y[e][1] = v1; y[e][2] = v2;
    }

    // out: 3 float4 contiguous stores (48B per thread)
    out4[(size_t)t * 3 + 0] = make_float4(y[0][0], y[0][1], y[0][2], y[1][0]);
    out4[(size_t)t * 3 + 1] = make_float4(y[1][1], y[1][2], y[2][0], y[2][1]);
    out4[(size_t)t * 3 + 2] = make_float4(y[2][2], y[3][0], y[3][1], y[3][2]);
}

extern "C" void kernel_launch(void* const* d_in, const int* in_sizes, int n_in,
                              void* d_out, int out_size, void* d_ws, size_t ws_size,
                              hipStream_t stream) {
    const float4* x4   = (const float4*)d_in[0];
    const float4* c4   = (const float4*)d_in[1];
    const float* psi   = (const float*)d_in[2];
    float4* out4 = (float4*)d_out;
    int B = in_sizes[0] / 3;   // x is [B,3,1]
    int nthread = B / 4;       // B divisible by 4

    int block = 256;
    int grid = (nthread + block - 1) / block;
    expm_apply4_kernel<<<grid, block, 0, stream>>>(x4, c4, psi, out4, nthread);
}

// Round 9
// 16.120 us; speedup vs baseline: 1.0958x; 1.0715x over previous
//
#include <hip/hip_runtime.h>
#include <math.h>

// B=1048576, M=6, N=3. R5 structure (measured best, 16.15us) with the only
// change being nontemporal global access (stream-once traffic -> bypass
// L2/L3 allocation). Uses clang ext_vector_type for the nt builtins since
// HIP's float2 class is rejected by __builtin_nontemporal_load.
// 1 element/thread, branch-free: fixed s=3 scaling + Pade(3,3) +
// adjugate solve + 8 fused mat-vecs. psi (54 floats) wave-uniform -> s_load.

typedef float vfloat2 __attribute__((ext_vector_type(2)));

// 3x3 row-major matmul: C = A*B
__device__ __forceinline__ void mm3(const float A[9], const float B[9], float C[9]) {
#pragma unroll
    for (int i = 0; i < 3; ++i) {
#pragma unroll
        for (int j = 0; j < 3; ++j) {
            C[i * 3 + j] = fmaf(A[i * 3 + 0], B[0 * 3 + j],
                           fmaf(A[i * 3 + 1], B[1 * 3 + j],
                                A[i * 3 + 2] * B[2 * 3 + j]));
        }
    }
}

__global__ __launch_bounds__(256) void expm_apply1_kernel(
    const float* __restrict__ x,     // [B,3]
    const float* __restrict__ c,     // [B,6]
    const float* __restrict__ psi,   // [54], wave-uniform
    float* __restrict__ out,         // [B,3]
    int B)
{
    int b = blockIdx.x * blockDim.x + threadIdx.x;
    if (b >= B) return;

    // Uniform pointer + constant indices -> s_load into SGPRs.
    float sp[54];
#pragma unroll
    for (int i = 0; i < 54; ++i) sp[i] = psi[i];

    // c[b,0..5]: 24B at 8B alignment -> 3x nontemporal 8B loads
    const vfloat2* c2 = reinterpret_cast<const vfloat2*>(c + (size_t)b * 6);
    vfloat2 ca = __builtin_nontemporal_load(&c2[0]);
    vfloat2 cb = __builtin_nontemporal_load(&c2[1]);
    vfloat2 cc = __builtin_nontemporal_load(&c2[2]);
    // fold the 2^-3 scaling into the coefficients: A = (sum c_m psi_m) / 8
    float cm[6] = {ca.x * 0.125f, ca.y * 0.125f, cb.x * 0.125f,
                   cb.y * 0.125f, cc.x * 0.125f, cc.y * 0.125f};

    // x[b,0..2]: nontemporal scalar loads
    float xv0 = __builtin_nontemporal_load(&x[(size_t)b * 3 + 0]);
    float xv1 = __builtin_nontemporal_load(&x[(size_t)b * 3 + 1]);
    float xv2 = __builtin_nontemporal_load(&x[(size_t)b * 3 + 2]);

    // A = (1/8) * sum_m c[m] * psi[m]   (SGPR operand on psi -> 1 fma each)
    float A[9];
#pragma unroll
    for (int i = 0; i < 9; ++i) {
        float acc = cm[0] * sp[i];
#pragma unroll
        for (int m = 1; m < 6; ++m) acc = fmaf(cm[m], sp[m * 9 + i], acc);
        A[i] = acc;
    }

    float A2[9];
    mm3(A, A, A2);

    // Pade(3,3): U = A*(A2 + 60I) = A^3 + 60A  (no temp matrix)
    float U[9];
    mm3(A, A2, U);
#pragma unroll
    for (int i = 0; i < 9; ++i) U[i] = fmaf(60.f, A[i], U[i]);

    // V = 12*A2 + 120I, never materialized: Mn = V-U, R = V+U directly.
    float Mn[9], R[9];
#pragma unroll
    for (int i = 0; i < 9; ++i) {
        float v = 12.f * A2[i];
        Mn[i] = v - U[i];
        R[i]  = v + U[i];
    }
    Mn[0] += 120.f; Mn[4] += 120.f; Mn[8] += 120.f;
    R[0]  += 120.f; R[4]  += 120.f; R[8]  += 120.f;

    // X = Mn^-1 R via adjugate; Mn ~ 120I - ..., det ~ 120^3, well-conditioned.
    float inv[9];
    inv[0] = Mn[4] * Mn[8] - Mn[5] * Mn[7];
    inv[1] = Mn[2] * Mn[7] - Mn[1] * Mn[8];
    inv[2] = Mn[1] * Mn[5] - Mn[2] * Mn[4];
    inv[3] = Mn[5] * Mn[6] - Mn[3] * Mn[8];
    inv[4] = Mn[0] * Mn[8] - Mn[2] * Mn[6];
    inv[5] = Mn[2] * Mn[3] - Mn[0] * Mn[5];
    inv[6] = Mn[3] * Mn[7] - Mn[4] * Mn[6];
    inv[7] = Mn[1] * Mn[6] - Mn[0] * Mn[7];
    inv[8] = Mn[0] * Mn[4] - Mn[1] * Mn[3];
    float det = Mn[0] * inv[0] + Mn[1] * inv[3] + Mn[2] * inv[6];
    float rdet = __builtin_amdgcn_rcpf(det);  // ~1e-6 rel, plenty for 2% tol

    float X[9];
    mm3(inv, R, X);
#pragma unroll
    for (int i = 0; i < 9; ++i) X[i] *= rdet;

    // y = X^(2^3) @ x = 8 fused mat-vecs (squarings folded into the apply)
    float v0 = xv0, v1 = xv1, v2 = xv2;
#pragma unroll
    for (int k = 0; k < 8; ++k) {
        float w0 = fmaf(X[0], v0, fmaf(X[1], v1, X[2] * v2));
        float w1 = fmaf(X[3], v0, fmaf(X[4], v1, X[5] * v2));
        float w2 = fmaf(X[6], v0, fmaf(X[7], v1, X[8] * v2));
        v0 = w0; v1 = w1; v2 = w2;
    }

    // nontemporal streaming stores
    __builtin_nontemporal_store(v0, &out[(size_t)b * 3 + 0]);
    __builtin_nontemporal_store(v1, &out[(size_t)b * 3 + 1]);
    __builtin_nontemporal_store(v2, &out[(size_t)b * 3 + 2]);
}

extern "C" void kernel_launch(void* const* d_in, const int* in_sizes, int n_in,
                              void* d_out, int out_size, void* d_ws, size_t ws_size,
                              hipStream_t stream) {
    const float* x   = (const float*)d_in[0];
    const float* c   = (const float*)d_in[1];
    const float* psi = (const float*)d_in[2];
    float* out = (float*)d_out;
    int B = in_sizes[0] / 3;   // x is [B,3,1]

    int block = 256;
    int grid = (B + block - 1) / block;
    expm_apply1_kernel<<<grid, block, 0, stream>>>(x, c, psi, out, B);
}